// Round 12
// baseline (197.499 us; speedup 1.0000x reference)
//
#include <hip/hip_runtime.h>

// MFMA fragment types (f16)
typedef _Float16 f16x8 __attribute__((ext_vector_type(8)));
typedef __fp16   fp16x2 __attribute__((ext_vector_type(2)));
typedef float f32x16 __attribute__((ext_vector_type(16)));

__device__ __forceinline__ unsigned pkrtz(float a, float b) {
    fp16x2 h = __builtin_amdgcn_cvt_pkrtz(a, b);   // src0->low, src1->high
    union { fp16x2 h; unsigned u; } c; c.h = h; return c.u;
}

__device__ __forceinline__ unsigned short f2h(float f) {
    _Float16 h = (_Float16)f;
    union { _Float16 h; unsigned short s; } c; c.h = h; return c.s;
}

// sigmoid((q·k)/8) with -0.125*log2e pre-folded into Q: s = 1/(1+2^t)
__device__ __forceinline__ float sig_from_t(float t) {
    return __builtin_amdgcn_rcpf(1.0f + __builtin_exp2f(t));
}

// ---------------------------------------------------------------------------
// wprep: one-shot transpose+f16 of the four 64x64 weight matrices.
// Wt[mat][j][k] f16  (so MFMA B/A frags read rows of W^T contiguously).
// ---------------------------------------------------------------------------
__global__ __launch_bounds__(256) void wprep_kernel(
    const float* __restrict__ w0, const float* __restrict__ w1,
    const float* __restrict__ w2, const float* __restrict__ w3,
    unsigned short* __restrict__ Wt)
{
    __shared__ float m[64][65];
    const float* src = (blockIdx.x == 0) ? w0 : (blockIdx.x == 1) ? w1
                     : (blockIdx.x == 2) ? w2 : w3;
    const int t = threadIdx.x;
    const int k = t >> 2, c0 = (t & 3) << 4;
    #pragma unroll
    for (int i = 0; i < 4; ++i)
        *(float4*)&m[k][c0 + i*4] = *(const float4*)&src[k*64 + c0 + i*4];
    __syncthreads();
    const int j = t >> 2, k0 = (t & 3) << 4;
    union { unsigned u[8]; uint4 v[2]; } o;
    #pragma unroll
    for (int p = 0; p < 8; ++p) o.u[p] = pkrtz(m[k0 + 2*p][j], m[k0 + 2*p + 1][j]);
    unsigned short* dst = Wt + blockIdx.x*4096 + j*64 + k0;
    *(uint4*)dst       = o.v[0];
    *(uint4*)(dst + 8) = o.v[1];
}

// ---------------------------------------------------------------------------
// prep (MFMA): per (b,bx) block, 64 tokens x 64 dims.
//   Xt[c][k] f16 staged in LDS (optionally fused fold: x1 = feature+g*sum P).
//   Q[c][j] = Xt·Wq^T rows + bq  -> Qg [b][4096][64] row-major
//   V -> Vtg [b][64][4096] transposed
// Wave w: token-tile tt=w&1, j-tile jt=w>>1; 8 MFMAs (4 k-steps x {Q,V}).
//   Q: mfma(A=Xt rows, B=Wqt rows) -> D[c][j], lane col=j  -> coalesced stores
//   V: mfma(A=Wvt rows, B=Xt rows) -> D[j][c], lane col=c  -> coalesced stores
// ---------------------------------------------------------------------------
__global__ __launch_bounds__(256) void prep_kernel(
    const float* __restrict__ src, const float* __restrict__ Pin,
    const float* __restrict__ gate,
    const unsigned short* __restrict__ Wqt, const unsigned short* __restrict__ Wvt,
    const float* __restrict__ bq, const float* __restrict__ bv,
    unsigned short* __restrict__ Qg, unsigned short* __restrict__ Vtg,
    float* __restrict__ x1out, int sK, int sF, int nsplit)
{
    __shared__ unsigned short Xt[64][76];   // 76-short row stride: 2-way banks (free)

    const int t = threadIdx.x;
    const int bx = blockIdx.x, b = blockIdx.y;

    {   // stage Xt (transposed slab) with optional inline fold_h
        const int c = t & 63, kq = t >> 6;   // kq uniform per wave
        const float g = Pin ? gate[0] : 0.f;
        float vals[16];
        #pragma unroll
        for (int kk = 0; kk < 16; ++kk) {
            const int k = kq*16 + kk;
            const size_t off = (size_t)k*sK + (size_t)bx*sF + c;
            float v = src[(size_t)b*262144 + off];
            if (Pin) {
                float s = 0.f;
                for (int ks = 0; ks < nsplit; ++ks)
                    s += Pin[((size_t)(ks*4 + b) << 18) + off];
                v += g * s;
                x1out[(size_t)b*262144 + off] = v;
            }
            vals[kk] = v;
        }
        union { unsigned u[8]; uint4 q[2]; } pk;
        #pragma unroll
        for (int p = 0; p < 8; ++p) pk.u[p] = pkrtz(vals[2*p], vals[2*p+1]);
        *(uint4*)&Xt[c][kq*16]     = pk.q[0];
        *(uint4*)&Xt[c][kq*16 + 8] = pk.q[1];
    }
    __syncthreads();

    const int lane = t & 63, w = t >> 6;
    const int l32 = lane & 31, hi = lane >> 5;
    const int tt = w & 1, jt = w >> 1;

    // Xt frags (A for Q, B for V — identical lane mapping): token = tt*32+l32
    f16x8 xf[4], wqf[4], wvf[4];
    #pragma unroll
    for (int s = 0; s < 4; ++s)
        xf[s] = *(const f16x8*)&Xt[tt*32 + l32][s*16 + hi*8];
    {   // W^T frags from global (32 KB total, L1-resident across all blocks)
        const unsigned short* qr = Wqt + (size_t)(jt*32 + l32)*64 + hi*8;
        const unsigned short* vr = Wvt + (size_t)(jt*32 + l32)*64 + hi*8;
        #pragma unroll
        for (int s = 0; s < 4; ++s) {
            wqf[s] = *(const f16x8*)(qr + s*16);
            wvf[s] = *(const f16x8*)(vr + s*16);
        }
    }

    f32x16 qa, va;
    #pragma unroll
    for (int i = 0; i < 16; ++i) { qa[i] = 0.f; va[i] = 0.f; }
    #pragma unroll
    for (int s = 0; s < 4; ++s) {
        qa = __builtin_amdgcn_mfma_f32_32x32x16_f16(xf[s], wqf[s], qa, 0,0,0);
        va = __builtin_amdgcn_mfma_f32_32x32x16_f16(wvf[s], xf[s], va, 0,0,0);
    }

    // Q epilogue: lane col j = jt*32+l32 (bias uniform/lane); rows = tokens
    const float bqv = bq[jt*32 + l32];
    const size_t qbase = (size_t)b*4096 + bx*64;
    #pragma unroll
    for (int r = 0; r < 16; ++r) {
        const int c = tt*32 + (r & 3) + 8*(r >> 2) + 4*hi;
        Qg[(qbase + c)*64 + jt*32 + l32] = f2h(qa[r] + bqv);
    }
    // V epilogue: lane col c = tt*32+l32; rows = j (bias per reg)
    const int ctok = bx*64 + tt*32 + l32;
    #pragma unroll
    for (int r = 0; r < 16; ++r) {
        const int j = jt*32 + (r & 3) + 8*(r >> 2) + 4*hi;
        Vtg[(size_t)b*262144 + (size_t)j*4096 + ctok] = f2h(va[r] + bv[j]);
    }
}

// ---------------------------------------------------------------------------
// attn (unchanged from r11): f16 MFMA 32x32x16; scale folded into Q frags;
// S transpose in registers via __shfl_xor(·,32); single-buffer K/V staging,
// reg prefetch, 2 barriers/iter; partial stores P[ksplit][b][d][token].
// ---------------------------------------------------------------------------
__global__ __launch_bounds__(256) void attn_kernel(
    const unsigned short* __restrict__ Qg,
    const unsigned short* __restrict__ Vtg,
    float* __restrict__ P)
{
    __shared__ unsigned short Ksh[64][72];
    __shared__ unsigned short Vts[64][72];

    const int t = threadIdx.x;
    const int mb = blockIdx.x, b = blockIdx.y, ksplit = blockIdx.z;
    const int nsp = gridDim.z;
    const int niter = 64 / nsp;
    const int keybase = ksplit * (4096 / nsp);
    const int lane = t & 63, w = t >> 6;
    const int l32 = lane & 31, hi = lane >> 5;

    const unsigned short* Qbase = Qg  + (size_t)b*262144;
    const unsigned short* Vbase = Vtg + (size_t)b*262144;

    // Q B-frags (n=query=l32, k=d=s*16+hi*8+j), scaled by -0.125*log2(e)
    f16x8 qb[4];
    {
        const unsigned short* qrow = Qbase + (size_t)(mb*128 + w*32 + l32)*64 + hi*8;
        const _Float16 sc = (_Float16)(-0.180336880f);
        #pragma unroll
        for (int s = 0; s < 4; ++s) {
            f16x8 q = *(const f16x8*)(qrow + s*16);
            qb[s] = q * sc;
        }
    }

    f32x16 y[2];
    #pragma unroll
    for (int i = 0; i < 16; ++i) { y[0][i] = 0.f; y[1][i] = 0.f; }

    const int lrow = t >> 2;
    const int loff = (t & 3) << 4;
    {   // prologue: stage tile 0
        const uint4* gk = (const uint4*)(Qbase + (size_t)(keybase + lrow)*64 + loff);
        uint4 k0 = gk[0], k1 = gk[1];
        const uint4* gv = (const uint4*)(Vbase + (size_t)lrow*4096 + keybase + loff);
        uint4 v0 = gv[0], v1 = gv[1];
        *(uint4*)&Ksh[lrow][loff]     = k0;
        *(uint4*)&Ksh[lrow][loff + 8] = k1;
        *(uint4*)&Vts[lrow][loff]     = v0;
        *(uint4*)&Vts[lrow][loff + 8] = v1;
    }
    __syncthreads();

    for (int kb = 0; kb < niter; ++kb) {
        // prefetch next tile into registers
        uint4 nk0 = {0,0,0,0}, nk1 = {0,0,0,0}, nv0 = {0,0,0,0}, nv1 = {0,0,0,0};
        if (kb < niter - 1) {
            const int keyn = keybase + (kb + 1)*64;
            const uint4* gk = (const uint4*)(Qbase + (size_t)(keyn + lrow)*64 + loff);
            nk0 = gk[0]; nk1 = gk[1];
            const uint4* gv = (const uint4*)(Vbase + (size_t)lrow*4096 + keyn + loff);
            nv0 = gv[0]; nv1 = gv[1];
        }

        // T = K·Qs^T : tt[u] covers keys u*32..+32 (scale pre-folded)
        f32x16 tt[2];
        #pragma unroll
        for (int i = 0; i < 16; ++i) { tt[0][i] = 0.f; tt[1][i] = 0.f; }
        #pragma unroll
        for (int s = 0; s < 4; ++s) {
            const int co = s*16 + hi*8;
            f16x8 ka0 = *(const f16x8*)&Ksh[l32][co];
            f16x8 ka1 = *(const f16x8*)&Ksh[32 + l32][co];
            tt[0] = __builtin_amdgcn_mfma_f32_32x32x16_f16(ka0, qb[s], tt[0], 0,0,0);
            tt[1] = __builtin_amdgcn_mfma_f32_32x32x16_f16(ka1, qb[s], tt[1], 0,0,0);
        }

        // per 32-key tile: sigmoid -> pack -> cross-half swap -> S·V MFMA
        #pragma unroll
        for (int u = 0; u < 2; ++u) {
            float sg[16];
            #pragma unroll
            for (int r = 0; r < 16; ++r) sg[r] = sig_from_t(tt[u][r]);
            #pragma unroll
            for (int ksh = 0; ksh < 2; ++ksh) {
                const int bR = ksh*8;
                unsigned Pa = pkrtz(sg[bR+0], sg[bR+1]);
                unsigned Pb = pkrtz(sg[bR+2], sg[bR+3]);
                unsigned Qa = pkrtz(sg[bR+4], sg[bR+5]);
                unsigned Qb = pkrtz(sg[bR+6], sg[bR+7]);
                unsigned xPa = __shfl_xor(Pa, 32);
                unsigned xPb = __shfl_xor(Pb, 32);
                unsigned xQa = __shfl_xor(Qa, 32);
                unsigned xQb = __shfl_xor(Qb, 32);
                union { unsigned u[4]; f16x8 v; } sa;
                sa.u[0] = hi ? xQa : Pa;
                sa.u[1] = hi ? xQb : Pb;
                sa.u[2] = hi ? Qa : xPa;
                sa.u[3] = hi ? Qb : xPb;

                const int ks = u*2 + ksh;           // absolute 16-key step
                const int co = ks*16 + hi*8;
                f16x8 vb0 = *(const f16x8*)&Vts[l32][co];
                f16x8 vb1 = *(const f16x8*)&Vts[32 + l32][co];
                y[0] = __builtin_amdgcn_mfma_f32_32x32x16_f16(sa.v, vb0, y[0], 0,0,0);
                y[1] = __builtin_amdgcn_mfma_f32_32x32x16_f16(sa.v, vb1, y[1], 0,0,0);
            }
        }

        __syncthreads();   // all waves done reading current tile
        if (kb < niter - 1) {
            *(uint4*)&Ksh[lrow][loff]     = nk0;
            *(uint4*)&Ksh[lrow][loff + 8] = nk1;
            *(uint4*)&Vts[lrow][loff]     = nv0;
            *(uint4*)&Vts[lrow][loff + 8] = nv1;
        }
        __syncthreads();   // next tile visible
    }

    // epilogue: P[ksplit][b][d][token]; token = mb*128 + w*32 + 8g + 4hi + e
    float* Pp = P + (((size_t)(ksplit*4 + b)) << 18);
    const int token0 = mb*128 + w*32 + hi*4;
    #pragma unroll
    for (int dt = 0; dt < 2; ++dt) {
        const int d = dt*32 + l32;
        #pragma unroll
        for (int g = 0; g < 4; ++g) {
            float4 v;
            v.x = y[dt][4*g+0]; v.y = y[dt][4*g+1];
            v.z = y[dt][4*g+2]; v.w = y[dt][4*g+3];
            *(float4*)&Pp[(size_t)d*4096 + token0 + 8*g] = v;
        }
    }
}

// ---------------------------------------------------------------------------
// final: out = p * (feature + x1 + g*sum_ks P_w[ks][b][d=w][token=h*64+c])
// ---------------------------------------------------------------------------
__global__ __launch_bounds__(256) void final_kernel(
    const float* __restrict__ feature, const float* __restrict__ x1,
    const float* __restrict__ Pin, const float* __restrict__ predict,
    const float* __restrict__ conv_w, const float* __restrict__ conv_b,
    const float* __restrict__ gate, float* __restrict__ out, int nsplit)
{
    const int i4 = blockIdx.x * 256 + threadIdx.x;   // [0, 262144)
    const int j = i4 << 2;
    const int pix = j >> 6;
    const float* row = predict + (size_t)pix * 19;
    float pv = conv_b[0];
    #pragma unroll
    for (int i = 0; i < 19; ++i) {
        float sg = __builtin_amdgcn_rcpf(1.0f + __builtin_exp2f(-1.442695041f * row[i]));
        pv += (1.0f - sg) * conv_w[i];
    }

    const int b = j >> 18, h = (j >> 12) & 63, d = (j >> 6) & 63, c = j & 63;
    const size_t pif = ((size_t)(b*64 + d) << 12) + h*64 + c;
    float sx = 0.f, sy = 0.f, sz = 0.f, sw = 0.f;
    for (int ks = 0; ks < nsplit; ++ks) {
        float4 pk = *(const float4*)&Pin[((size_t)ks << 20) + pif];
        sx += pk.x; sy += pk.y; sz += pk.z; sw += pk.w;
    }
    const float g = gate[0];
    float4 f = ((const float4*)feature)[i4];
    float4 x = ((const float4*)x1)[i4];
    float4 o;
    o.x = pv * (f.x + x.x + g * sx);
    o.y = pv * (f.y + x.y + g * sy);
    o.z = pv * (f.z + x.z + g * sz);
    o.w = pv * (f.w + x.w + g * sw);
    ((float4*)out)[i4] = o;
}

extern "C" void kernel_launch(void* const* d_in, const int* in_sizes, int n_in,
                              void* d_out, int out_size, void* d_ws, size_t ws_size,
                              hipStream_t stream) {
    const float* feature = (const float*)d_in[0];
    const float* predict = (const float*)d_in[1];
    const float* hq_w = (const float*)d_in[2];
    const float* hq_b = (const float*)d_in[3];
    const float* hv_w = (const float*)d_in[4];
    const float* hv_b = (const float*)d_in[5];
    const float* wq_w = (const float*)d_in[6];
    const float* wq_b = (const float*)d_in[7];
    const float* wv_w = (const float*)d_in[8];
    const float* wv_b = (const float*)d_in[9];
    const float* h_gate = (const float*)d_in[10];
    const float* w_gate = (const float*)d_in[11];
    const float* conv_w = (const float*)d_in[12];
    const float* conv_b = (const float*)d_in[13];
    float* out = (float*)d_out;

    // workspace: Qg 2MB | Vtg 2MB | x1 4MB | P 16MB | Wt 32KB  (24.03 MiB)
    char* ws = (char*)d_ws;
    unsigned short* Qg  = (unsigned short*)(ws);
    unsigned short* Vtg = (unsigned short*)(ws + (2u << 20));
    float*          x1  = (float*)(ws + (4u << 20));
    float*          P   = (float*)(ws + (8u << 20));
    unsigned short* Wt  = (unsigned short*)(ws + (24u << 20));
    const int nsplit = 4;

    dim3 blk(256);
    // one-shot: W^T f16 for all four matrices (mat0=hq, mat1=hv, mat2=wq, mat3=wv)
    wprep_kernel<<<dim3(4), blk, 0, stream>>>(hq_w, hv_w, wq_w, wv_w, Wt);
    // height stage (no fold)
    prep_kernel<<<dim3(64, 4), blk, 0, stream>>>(feature, nullptr, nullptr,
                                                 Wt, Wt + 4096, hq_b, hv_b,
                                                 Qg, Vtg, nullptr, 4096, 64, 0);
    attn_kernel<<<dim3(32, 4, nsplit), blk, 0, stream>>>(Qg, Vtg, P);
    // width stage: x1 = feature + h_gate*sum(P) fused into staging
    prep_kernel<<<dim3(64, 4), blk, 0, stream>>>(feature, P, h_gate,
                                                 Wt + 8192, Wt + 12288, wq_b, wv_b,
                                                 Qg, Vtg, x1, 64, 4096, nsplit);
    attn_kernel<<<dim3(32, 4, nsplit), blk, 0, stream>>>(Qg, Vtg, P);
    // out = p * (feature + x1 + w_gate*sum(P))
    final_kernel<<<dim3(1024), blk, 0, stream>>>(feature, x1, P, predict,
                                                 conv_w, conv_b, w_gate, out, nsplit);
}

// Round 14
// 188.809 us; speedup vs baseline: 1.0460x; 1.0460x over previous
//
#include <hip/hip_runtime.h>

// MFMA fragment types (f16)
typedef _Float16 f16x8 __attribute__((ext_vector_type(8)));
typedef __fp16   fp16x2 __attribute__((ext_vector_type(2)));
typedef float f32x16 __attribute__((ext_vector_type(16)));

__device__ __forceinline__ unsigned pkrtz(float a, float b) {
    fp16x2 h = __builtin_amdgcn_cvt_pkrtz(a, b);   // src0->low, src1->high
    union { fp16x2 h; unsigned u; } c; c.h = h; return c.u;
}

__device__ __forceinline__ unsigned short f2h(float f) {
    _Float16 h = (_Float16)f;
    union { _Float16 h; unsigned short s; } c; c.h = h; return c.s;
}

// ---------------------------------------------------------------------------
// prep (height stage, r11-proven): per (b, bx=w) block: slab[k=h][c],
//   Q -> Qg [b][4096][64] f16 row-major ; V -> Vtg [b][64][4096] f16 (T)
// ---------------------------------------------------------------------------
__global__ __launch_bounds__(256) void prep_kernel(
    const float* __restrict__ src,
    const float* __restrict__ wq, const float* __restrict__ bq,
    const float* __restrict__ wv, const float* __restrict__ bv,
    unsigned short* __restrict__ Qg, unsigned short* __restrict__ Vtg)
{
    __shared__ float slab[64][65];
    __shared__ float wqs[4096];
    __shared__ float wvs[4096];

    const int t  = threadIdx.x;
    const int bx = blockIdx.x, b = blockIdx.y;

    {   // stage weights
        const float4* wq4 = (const float4*)wq;
        const float4* wv4 = (const float4*)wv;
        float4* q4 = (float4*)wqs; float4* v4 = (float4*)wvs;
        #pragma unroll
        for (int i = 0; i < 4; ++i) {
            q4[i*256 + t] = wq4[i*256 + t];
            v4[i*256 + t] = wv4[i*256 + t];
        }
    }
    {   // stage slab: k=h rows (stride 4096), bx=w fixed
        const int k = t >> 2, c0 = (t & 3) << 4;
        const size_t sb = (size_t)b*262144 + (size_t)k*4096 + (size_t)bx*64 + c0;
        #pragma unroll
        for (int i = 0; i < 4; ++i)
            *(float4*)&slab[k][c0 + i*4] = *(const float4*)&src[sb + i*4];
    }
    __syncthreads();

    const int c = t & 63, jg = t >> 6;
    float qa[16], va[16];
    #pragma unroll
    for (int jj = 0; jj < 16; ++jj) { qa[jj] = bq[jg*16+jj]; va[jj] = bv[jg*16+jj]; }
    for (int k = 0; k < 64; ++k) {
        const float xv = slab[k][c];
        const float* wqr = &wqs[k*64 + jg*16];
        const float* wvr = &wvs[k*64 + jg*16];
        #pragma unroll
        for (int jj = 0; jj < 16; ++jj) {
            qa[jj] += xv * wqr[jj];
            va[jj] += xv * wvr[jj];
        }
    }
    const int token = bx*64 + c;
    union { unsigned u[8]; uint4 v[2]; } qp;
    #pragma unroll
    for (int jj = 0; jj < 8; ++jj) qp.u[jj] = pkrtz(qa[2*jj], qa[2*jj+1]);
    const size_t qoff = ((size_t)b*4096 + token)*64 + jg*16;
    *(uint4*)&Qg[qoff]     = qp.v[0];
    *(uint4*)&Qg[qoff + 8] = qp.v[1];
    #pragma unroll
    for (int jj = 0; jj < 16; ++jj)
        Vtg[((size_t)b*64 + jg*16 + jj)*4096 + token] = f2h(va[jj]);
}

// ---------------------------------------------------------------------------
// prep_w (width stage, r11-proven) FUSED with fold_h:
//   x1 = feature + g*sum_ks(P_h) computed during slab staging, then Q/V GEMM.
// ---------------------------------------------------------------------------
__global__ __launch_bounds__(256) void prep_w_kernel(
    const float* __restrict__ feature, const float* __restrict__ Pin,
    const float* __restrict__ gate,
    const float* __restrict__ wq, const float* __restrict__ bq,
    const float* __restrict__ wv, const float* __restrict__ bv,
    unsigned short* __restrict__ Qg, unsigned short* __restrict__ Vtg,
    float* __restrict__ x1out, int nsplit)
{
    __shared__ float slab[64][65];
    __shared__ float wqs[4096];
    __shared__ float wvs[4096];

    const int t  = threadIdx.x;
    const int bx = blockIdx.x, b = blockIdx.y;   // bx = h

    {   // stage weights
        const float4* wq4 = (const float4*)wq;
        const float4* wv4 = (const float4*)wv;
        float4* q4 = (float4*)wqs; float4* v4 = (float4*)wvs;
        #pragma unroll
        for (int i = 0; i < 4; ++i) {
            q4[i*256 + t] = wq4[i*256 + t];
            v4[i*256 + t] = wv4[i*256 + t];
        }
    }
    {   // stage slab with inline fold: P_h[ks][b][d=h][token=w*64+c]
        const int k = t >> 2, c0 = (t & 3) << 4;
        const size_t off = (size_t)bx*4096 + (size_t)k*64 + c0;  // h*4096 + w*64 + c
        const size_t fb  = (size_t)b*262144 + off;
        const float g = gate[0];
        #pragma unroll
        for (int i = 0; i < 4; ++i) {
            float4 v  = *(const float4*)&feature[fb + i*4];
            float sx = 0.f, sy = 0.f, sz = 0.f, sw = 0.f;
            for (int ks = 0; ks < nsplit; ++ks) {
                float4 pk = *(const float4*)&Pin[((size_t)(ks*4 + b) << 18) + off + i*4];
                sx += pk.x; sy += pk.y; sz += pk.z; sw += pk.w;
            }
            v.x += g * sx; v.y += g * sy; v.z += g * sz; v.w += g * sw;
            *(float4*)&slab[k][c0 + i*4] = v;
            *(float4*)&x1out[fb + i*4] = v;
        }
    }
    __syncthreads();

    const int c = t & 63, jg = t >> 6;
    float qa[16], va[16];
    #pragma unroll
    for (int jj = 0; jj < 16; ++jj) { qa[jj] = bq[jg*16+jj]; va[jj] = bv[jg*16+jj]; }
    for (int k = 0; k < 64; ++k) {
        const float xv = slab[k][c];
        const float* wqr = &wqs[k*64 + jg*16];
        const float* wvr = &wvs[k*64 + jg*16];
        #pragma unroll
        for (int jj = 0; jj < 16; ++jj) {
            qa[jj] += xv * wqr[jj];
            va[jj] += xv * wvr[jj];
        }
    }
    const int token = bx*64 + c;
    union { unsigned u[8]; uint4 v[2]; } qp;
    #pragma unroll
    for (int jj = 0; jj < 8; ++jj) qp.u[jj] = pkrtz(qa[2*jj], qa[2*jj+1]);
    const size_t qoff = ((size_t)b*4096 + token)*64 + jg*16;
    *(uint4*)&Qg[qoff]     = qp.v[0];
    *(uint4*)&Qg[qoff + 8] = qp.v[1];
    #pragma unroll
    for (int jj = 0; jj < 16; ++jj)
        Vtg[((size_t)b*64 + jg*16 + jj)*4096 + token] = f2h(va[jj]);
}

// ---------------------------------------------------------------------------
// attn v14 = v13 + overflow clamp. f16 32x32x16 MFMA, no cross-lane S moves:
// V staged with per-16 key permutation nu (swap middle 4-groups; self-inverse)
// so the S·V A-frag for step sp is exactly C-regs [8sp..8sp+7] of T = K·Q^T
// (verified: kappa_A(hi,j) == nu(slot(hi,j)) for all hi,j).
// Sigmoid pairwise: ONE rcp per 2 scores; t clamped <= 60 so d0*d1 can't
// reach inf (r13's NaN: rcp(inf)=0 times inf partner = NaN).
// LDS ping-pong: ONE barrier/iter. Epilogue: partial stores P[ks][b][d][tok].
// ---------------------------------------------------------------------------
__global__ __launch_bounds__(256) void attn_kernel(
    const unsigned short* __restrict__ Qg,
    const unsigned short* __restrict__ Vtg,
    float* __restrict__ P)
{
    __shared__ unsigned short Ksh[2][64][72];
    __shared__ unsigned short Vts[2][64][72];

    const int t = threadIdx.x;
    const int mb = blockIdx.x, b = blockIdx.y, ksplit = blockIdx.z;
    const int nsp = gridDim.z;
    const int niter = 64 / nsp;
    const int keybase = ksplit * (4096 / nsp);
    const int lane = t & 63, w = t >> 6;
    const int l32 = lane & 31, hi = lane >> 5;

    const unsigned short* Qbase = Qg  + (size_t)b*262144;
    const unsigned short* Vbase = Vtg + (size_t)b*262144;

    // Q B-frags (n=query=l32, k=d=s*16+hi*8+j), scaled by -0.125*log2(e)
    f16x8 qb[4];
    {
        const unsigned short* qrow = Qbase + (size_t)(mb*128 + w*32 + l32)*64 + hi*8;
        const _Float16 sc = (_Float16)(-0.180336880f);
        #pragma unroll
        for (int s = 0; s < 4; ++s) {
            f16x8 q = *(const f16x8*)(qrow + s*16);
            qb[s] = q * sc;
        }
    }

    f32x16 y[2];
    #pragma unroll
    for (int i = 0; i < 16; ++i) { y[0][i] = 0.f; y[1][i] = 0.f; }

    const int lrow = t >> 2;
    const int loff = (t & 3) << 4;   // 16-key block per staging quarter
    {   // prologue: stage tile 0 into buffer 0 (V with nu swizzle)
        const uint4* gk = (const uint4*)(Qbase + (size_t)(keybase + lrow)*64 + loff);
        uint4 k0 = gk[0], k1 = gk[1];
        const uint4* gv = (const uint4*)(Vbase + (size_t)lrow*4096 + keybase + loff);
        uint4 v0 = gv[0], v1 = gv[1];
        *(uint4*)&Ksh[0][lrow][loff]     = k0;
        *(uint4*)&Ksh[0][lrow][loff + 8] = k1;
        uint4 pa = { v0.x, v0.y, v1.x, v1.y };   // slots 0-7 = keys 0-3,8-11
        uint4 pb = { v0.z, v0.w, v1.z, v1.w };   // slots 8-15 = keys 4-7,12-15
        *(uint4*)&Vts[0][lrow][loff]     = pa;
        *(uint4*)&Vts[0][lrow][loff + 8] = pb;
    }
    __syncthreads();

    for (int kb = 0; kb < niter; ++kb) {
        const int cur = kb & 1, nxt = cur ^ 1;

        // prefetch next tile into registers (in flight across compute phase)
        uint4 nk0 = {0,0,0,0}, nk1 = {0,0,0,0}, nv0 = {0,0,0,0}, nv1 = {0,0,0,0};
        if (kb < niter - 1) {
            const int keyn = keybase + (kb + 1)*64;
            const uint4* gk = (const uint4*)(Qbase + (size_t)(keyn + lrow)*64 + loff);
            nk0 = gk[0]; nk1 = gk[1];
            const uint4* gv = (const uint4*)(Vbase + (size_t)lrow*4096 + keyn + loff);
            nv0 = gv[0]; nv1 = gv[1];
        }

        // T = K·Qs^T : tt[u] covers keys u*32..+32 (scale pre-folded)
        f32x16 tt[2];
        #pragma unroll
        for (int i = 0; i < 16; ++i) { tt[0][i] = 0.f; tt[1][i] = 0.f; }
        #pragma unroll
        for (int s = 0; s < 4; ++s) {
            const int co = s*16 + hi*8;
            f16x8 ka0 = *(const f16x8*)&Ksh[cur][l32][co];
            f16x8 ka1 = *(const f16x8*)&Ksh[cur][32 + l32][co];
            tt[0] = __builtin_amdgcn_mfma_f32_32x32x16_f16(ka0, qb[s], tt[0], 0,0,0);
            tt[1] = __builtin_amdgcn_mfma_f32_32x32x16_f16(ka1, qb[s], tt[1], 0,0,0);
        }

        // sigmoid (pairwise rcp, t clamped) -> pack -> DIRECT A-frag
        #pragma unroll
        for (int u = 0; u < 2; ++u) {
            unsigned pk_[8];
            #pragma unroll
            for (int pr = 0; pr < 8; ++pr) {
                float t0 = __builtin_fminf(tt[u][2*pr+0], 60.0f);
                float t1 = __builtin_fminf(tt[u][2*pr+1], 60.0f);
                float e0 = __builtin_exp2f(t0);
                float e1 = __builtin_exp2f(t1);
                float d0 = 1.0f + e0, d1 = 1.0f + e1;
                float rr = __builtin_amdgcn_rcpf(d0 * d1);
                pk_[pr] = pkrtz(rr * d1, rr * d0);
            }
            #pragma unroll
            for (int sp = 0; sp < 2; ++sp) {
                union { unsigned u4[4]; f16x8 v; } sa;
                sa.u4[0] = pk_[sp*4 + 0];
                sa.u4[1] = pk_[sp*4 + 1];
                sa.u4[2] = pk_[sp*4 + 2];
                sa.u4[3] = pk_[sp*4 + 3];
                const int ks = u*2 + sp;
                const int co = ks*16 + hi*8;
                f16x8 vb0 = *(const f16x8*)&Vts[cur][l32][co];
                f16x8 vb1 = *(const f16x8*)&Vts[cur][32 + l32][co];
                y[0] = __builtin_amdgcn_mfma_f32_32x32x16_f16(sa.v, vb0, y[0], 0,0,0);
                y[1] = __builtin_amdgcn_mfma_f32_32x32x16_f16(sa.v, vb1, y[1], 0,0,0);
            }
        }

        // drain prefetch into the idle buffer (nobody reads nxt this iter)
        if (kb < niter - 1) {
            *(uint4*)&Ksh[nxt][lrow][loff]     = nk0;
            *(uint4*)&Ksh[nxt][lrow][loff + 8] = nk1;
            uint4 pa = { nv0.x, nv0.y, nv1.x, nv1.y };
            uint4 pb = { nv0.z, nv0.w, nv1.z, nv1.w };
            *(uint4*)&Vts[nxt][lrow][loff]     = pa;
            *(uint4*)&Vts[nxt][lrow][loff + 8] = pb;
        }
        __syncthreads();   // single barrier per iteration
    }

    // epilogue: P[ksplit][b][d][token]; token = mb*128 + w*32 + 8g + 4hi + e
    float* Pp = P + (((size_t)(ksplit*4 + b)) << 18);
    const int token0 = mb*128 + w*32 + hi*4;
    #pragma unroll
    for (int dt = 0; dt < 2; ++dt) {
        const int d = dt*32 + l32;
        #pragma unroll
        for (int g = 0; g < 4; ++g) {
            float4 v;
            v.x = y[dt][4*g+0]; v.y = y[dt][4*g+1];
            v.z = y[dt][4*g+2]; v.w = y[dt][4*g+3];
            *(float4*)&Pp[(size_t)d*4096 + token0 + 8*g] = v;
        }
    }
}

// ---------------------------------------------------------------------------
// final: out = p * (feature + x1 + g*sum_ks P_w[ks][b][d=w][token=h*64+c])
// ---------------------------------------------------------------------------
__global__ __launch_bounds__(256) void final_kernel(
    const float* __restrict__ feature, const float* __restrict__ x1,
    const float* __restrict__ Pin, const float* __restrict__ predict,
    const float* __restrict__ conv_w, const float* __restrict__ conv_b,
    const float* __restrict__ gate, float* __restrict__ out, int nsplit)
{
    const int i4 = blockIdx.x * 256 + threadIdx.x;   // [0, 262144)
    const int j = i4 << 2;
    const int pix = j >> 6;
    const float* row = predict + (size_t)pix * 19;
    float pv = conv_b[0];
    #pragma unroll
    for (int i = 0; i < 19; ++i) {
        float sg = __builtin_amdgcn_rcpf(1.0f + __builtin_exp2f(-1.442695041f * row[i]));
        pv += (1.0f - sg) * conv_w[i];
    }

    const int b = j >> 18, h = (j >> 12) & 63, d = (j >> 6) & 63, c = j & 63;
    const size_t pif = ((size_t)(b*64 + d) << 12) + h*64 + c;
    float sx = 0.f, sy = 0.f, sz = 0.f, sw = 0.f;
    for (int ks = 0; ks < nsplit; ++ks) {
        float4 pk = *(const float4*)&Pin[((size_t)ks << 20) + pif];
        sx += pk.x; sy += pk.y; sz += pk.z; sw += pk.w;
    }
    const float g = gate[0];
    float4 f = ((const float4*)feature)[i4];
    float4 x = ((const float4*)x1)[i4];
    float4 o;
    o.x = pv * (f.x + x.x + g * sx);
    o.y = pv * (f.y + x.y + g * sy);
    o.z = pv * (f.z + x.z + g * sz);
    o.w = pv * (f.w + x.w + g * sw);
    ((float4*)out)[i4] = o;
}

extern "C" void kernel_launch(void* const* d_in, const int* in_sizes, int n_in,
                              void* d_out, int out_size, void* d_ws, size_t ws_size,
                              hipStream_t stream) {
    const float* feature = (const float*)d_in[0];
    const float* predict = (const float*)d_in[1];
    const float* hq_w = (const float*)d_in[2];
    const float* hq_b = (const float*)d_in[3];
    const float* hv_w = (const float*)d_in[4];
    const float* hv_b = (const float*)d_in[5];
    const float* wq_w = (const float*)d_in[6];
    const float* wq_b = (const float*)d_in[7];
    const float* wv_w = (const float*)d_in[8];
    const float* wv_b = (const float*)d_in[9];
    const float* h_gate = (const float*)d_in[10];
    const float* w_gate = (const float*)d_in[11];
    const float* conv_w = (const float*)d_in[12];
    const float* conv_b = (const float*)d_in[13];
    float* out = (float*)d_out;

    // workspace: Qg 2MB | Vtg 2MB | x1 4MB | P nsplit*4MB (nsplit=4 -> 24 MiB)
    char* ws = (char*)d_ws;
    unsigned short* Qg  = (unsigned short*)(ws);
    unsigned short* Vtg = (unsigned short*)(ws + (2u << 20));
    float*          x1  = (float*)(ws + (4u << 20));
    float*          P   = (float*)(ws + (8u << 20));
    const int nsplit = 4;

    dim3 blk(256);
    // height stage
    prep_kernel<<<dim3(64, 4), blk, 0, stream>>>(feature, hq_w, hq_b, hv_w, hv_b,
                                                 Qg, Vtg);
    attn_kernel<<<dim3(32, 4, nsplit), blk, 0, stream>>>(Qg, Vtg, P);
    // width stage: x1 = feature + h_gate*sum(P) fused into staging
    prep_w_kernel<<<dim3(64, 4), blk, 0, stream>>>(feature, P, h_gate,
                                                   wq_w, wq_b, wv_w, wv_b,
                                                   Qg, Vtg, x1, nsplit);
    attn_kernel<<<dim3(32, 4, nsplit), blk, 0, stream>>>(Qg, Vtg, P);
    // out = p * (feature + x1 + w_gate*sum(P))
    final_kernel<<<dim3(1024), blk, 0, stream>>>(feature, x1, P, predict,
                                                 conv_w, conv_b, w_gate, out, nsplit);
}